// Round 9
// baseline (279.341 us; speedup 1.0000x reference)
//
#include <hip/hip_runtime.h>
#include <hip/hip_bf16.h>
#include <cstddef>

// 3-layer tanh RNN (B=8192, T=80, D=32, H=64), fused, MFMA.
// SYSTOLIC LAYER PIPELINE, 4-STEP CHUNKS, register-carried recurrence (K=32).
// R20: HALF-TILE OCCUPANCY - M=8 rows/block, 1024 blocks, 3 waves/SIMD.
//
// R19 post-mortem: late-pack regressed (wave-0 tail past publish). R18 base.
// Counter-closed model (R12-R19): s~1.9k cyc/step-slot; per-wave VALU ~480cyc
// (VALUBusy 38% @1.5w/SIMD), MFMA ~195, stall ~47%. Latency-bound with idle
// issue capacity -> need more streams/SIMD. This round: 8 batch rows/block,
// 1024 blocks = 12 waves/CU = 3 waves/SIMD (LDS 147KB/CU, VGPR 96 ok).
// Per-wave work unchanged (16-wide MFMA tile, 8 valid cols); total issue 2x
// but per-SIMD VALU demand 3x480=1440 < 1900 -> wall drops if stalls overlap.
// Output cols are independent in every op (MFMA D-col, tanh, publish), so
// valid rows are BIT-IDENTICAL; garbage cols stay finite (rcp(inf)=0).
//
// Structure (R18, best measured 73.5-75.2us):
//   - wave wv = layer wv; interval m (0..21): t = 4*(m-wv)..+3; ONE barrier
//     per interval; LDS ring hb[layer<2][t&7][16][72] (36864 B);
//     reader slots (lt0-4..-1)&7, writer (lt0..+3)&7, upstream (lt0+4..+7)&7
//     - pairwise disjoint mod 8;
//   - recurrence register-carried at K=32 via k-permuted Whh frags
//     (slot i = h[32h+16(i>>2)+4q+(i&3)], bijection folded into weight gather);
//   - wave-0 x double-buffered raw (fx4), packed at interval top, refill
//     issued after packing, consumed next interval;
//   - publishes deferred to interval end (R17);
//   - tanh: exp2 (bias pre-scaled by 2*log2e) + paired rcp (R18).
// MFMA maps (verified R2-R11):
//   K=32 A: A[m=lane&15][k=8q+i]; B: B[k=8q+i][n=lane&15]  (q=lane>>4)
//   16x16 D: D[row=4q+r][col=lane&15]

typedef __attribute__((ext_vector_type(8))) short s16x8;
typedef __attribute__((ext_vector_type(4))) short s16x4;
typedef __attribute__((ext_vector_type(4))) float fx4;

#define MFMA32(A, B, C) __builtin_amdgcn_mfma_f32_16x16x32_bf16((A), (B), (C), 0, 0, 0)

#if __has_builtin(__builtin_amdgcn_exp2f)
#define EXP2F(x) __builtin_amdgcn_exp2f(x)
#else
#define EXP2F(x) exp2f(x)
#endif
#if __has_builtin(__builtin_amdgcn_rcpf)
#define RCPF(x) __builtin_amdgcn_rcpf(x)
#else
#define RCPF(x) (1.0f / (x))
#endif

static constexpr float K2LOG2E = 2.8853900817779268f;  // 2*log2(e)

__device__ __forceinline__ short f2bf(float f) {  // RNE float->bf16 (weights, one-time)
  union { float f; unsigned u; } v; v.f = f;
  unsigned r = v.u + 0x7FFFu + ((v.u >> 16) & 1u);
  return (short)(r >> 16);
}
__device__ __forceinline__ float bf2f(short s) {
  union { unsigned u; float f; } v; v.u = ((unsigned)(unsigned short)s) << 16;
  return v.f;
}
__device__ __forceinline__ unsigned pk2bf(float a, float b) {  // v_cvt_pk_bf16_f32
  float2 t; t.x = a; t.y = b;
  union { __hip_bfloat162 h; unsigned u; } c;
  c.h = __float22bfloat162_rn(t);
  return c.u;
}

__device__ __forceinline__ s16x8 wfragA32(const float* W, int ncols, int row, int col0) {
  const float* p = W + row * ncols + col0;
  s16x8 r;
#pragma unroll
  for (int i = 0; i < 8; ++i) r[i] = f2bf(p[i]);
  return r;
}

// k-permuted Whh A-frag for the K=32 register-carried recurrence (half h=0,1):
// slot i  <-  Whh[row][ 32h + 16*(i>>2) + 4q + (i&3) ]
__device__ __forceinline__ s16x8 wfragWhh32(const float* W, int row, int q, int h) {
  const float* p = W + row * 64 + 32 * h + 4 * q;
  s16x8 r;
#pragma unroll
  for (int i = 0; i < 4; ++i) r[i] = f2bf(p[i]);
#pragma unroll
  for (int i = 0; i < 4; ++i) r[4 + i] = f2bf(p[16 + i]);
  return r;
}

// tanh(acc + bias) (bias pre-scaled by 2*log2e) -> packed bf16.
// PAIRED RCP: rp = rcp(a0*a1); 1/a0 = a1*rp; 1/a1 = a0*rp
__device__ __forceinline__ s16x4 tanh_pack(fx4 acc, const float* bs) {
  float a[4], h[4];
#pragma unroll
  for (int r = 0; r < 4; ++r)
    a[r] = EXP2F(__builtin_fmaf(acc[r], K2LOG2E, bs[r])) + 1.f;
#pragma unroll
  for (int pr = 0; pr < 2; ++pr) {
    float p  = a[2 * pr] * a[2 * pr + 1];
    float rp = RCPF(p);
    float m0 = a[2 * pr + 1] * rp;     // = 1/a0
    float m1 = a[2 * pr] * rp;         // = 1/a1
    h[2 * pr]     = __builtin_fmaf(-2.f, m0, 1.f);
    h[2 * pr + 1] = __builtin_fmaf(-2.f, m1, 1.f);
  }
  union { unsigned u[2]; s16x4 v; } pk;
  pk.u[0] = pk2bf(h[0], h[1]);
  pk.u[1] = pk2bf(h[2], h[3]);
  return pk.v;
}

union U8 { s16x8 v; s16x4 h[2]; };

__global__ __launch_bounds__(192, 3) void rnn3_half(
    const float* __restrict__ x,
    const float* __restrict__ Wih0, const float* __restrict__ Whh0,
    const float* __restrict__ bih0, const float* __restrict__ bhh0,
    const float* __restrict__ Wih1, const float* __restrict__ Whh1,
    const float* __restrict__ bih1, const float* __restrict__ bhh1,
    const float* __restrict__ Wih2, const float* __restrict__ Whh2,
    const float* __restrict__ bih2, const float* __restrict__ bhh2,
    const float* __restrict__ Wfc, const float* __restrict__ bfc,
    float* __restrict__ out)
{
  __shared__ __align__(16) short hb[2][8][16][72];  // [layer<2][t&7][col][j], 36864 B

  const int tid = threadIdx.x;
  const int wv  = __builtin_amdgcn_readfirstlane(tid >> 6);  // 0..2 == layer
  const int ln  = tid & 63;
  const int q   = ln >> 4;        // K=32 k-quad / D row-quad
  const int m15 = ln & 15;
  const int bbase = (int)blockIdx.x * 8;     // 8 valid batch rows per block

  // ---------- this wave's layer parameters ----------
  const float* Wih = (wv == 0) ? Wih0 : (wv == 1) ? Wih1 : Wih2;
  const float* Whh = (wv == 0) ? Whh0 : (wv == 1) ? Whh1 : Whh2;
  const float* bi  = (wv == 0) ? bih0 : (wv == 1) ? bih1 : bih2;
  const float* bh  = (wv == 0) ? bhh0 : (wv == 1) ? bhh1 : bhh2;
  const int kin = (wv == 0) ? 32 : 64;

  // ---------- weights (VGPR-resident) ----------
  s16x8 wiA[4], wiB[4];
  s16x8 wh32[4][2];
  const s16x8 z8 = {0, 0, 0, 0, 0, 0, 0, 0};
#pragma unroll
  for (int t4 = 0; t4 < 4; ++t4) {
    const int row = 16 * t4 + m15;
    wiA[t4] = wfragA32(Wih, kin, row, 8 * q);
    wiB[t4] = wv ? wfragA32(Wih, 64, row, 32 + 8 * q) : z8;   // layer 0: K=32 only
    wh32[t4][0] = wfragWhh32(Whh, row, q, 0);
    wh32[t4][1] = wfragWhh32(Whh, row, q, 1);
  }

  // ---------- biases pre-scaled; lane's j = 16*t4 + 4*q + r ----------
  float bsc[4][4];
#pragma unroll
  for (int t4 = 0; t4 < 4; ++t4)
#pragma unroll
    for (int r = 0; r < 4; ++r) {
      const int j = 16 * t4 + 4 * q + r;
      bsc[t4][r] = (bi[j] + bh[j]) * K2LOG2E;
    }

  const fx4 z4 = {0.f, 0.f, 0.f, 0.f};
  U8 hA, hB;                       // own state h_wv(t-1): hA=(j 0..31), hB=(j 32..63)
  hA.v = z8; hB.v = z8;

  // ---------- wave-0 x buffer: 4 t's of this interval (raw fx4) ----------
  // cols 8..15 duplicate neighbor rows (clamped at B-1): finite garbage only.
  const int xrow = (bbase + m15 <= 8191) ? bbase + m15 : 8191;
  const float* xr = x + (size_t)xrow * (80 * 32) + 8 * q;
  fx4 xb0[4], xb1[4];
  if (wv == 0) {
#pragma unroll
    for (int jj = 0; jj < 4; ++jj) {          // preload t = 0..3
      xb0[jj] = *(const fx4*)(xr + jj * 32);
      xb1[jj] = *(const fx4*)(xr + jj * 32 + 4);
    }
  }

  for (int m = 0; m < 22; ++m) {
    const int lt0 = 4 * (m - wv);             // first t of this interval
    if (0 <= lt0 && lt0 <= 76) {              // wave-uniform
      // ---- interval top: gather all 4 inputs ----
      s16x8 inA[4], inB[4];
      if (wv == 0) {
#pragma unroll
        for (int jj = 0; jj < 4; ++jj) {
          union { unsigned u[4]; s16x8 v; } xp;
          xp.u[0] = pk2bf(xb0[jj][0], xb0[jj][1]);
          xp.u[1] = pk2bf(xb0[jj][2], xb0[jj][3]);
          xp.u[2] = pk2bf(xb1[jj][0], xb1[jj][1]);
          xp.u[3] = pk2bf(xb1[jj][2], xb1[jj][3]);
          inA[jj] = xp.v; inB[jj] = z8;
        }
        // refill for next interval (t = lt0+4 .. lt0+7, clamped); issued now,
        // consumed at NEXT interval top -> full interval to land
#pragma unroll
        for (int jj = 0; jj < 4; ++jj) {
          const int tt = (lt0 + 4 + jj <= 79) ? lt0 + 4 + jj : 79;
          xb0[jj] = *(const fx4*)(xr + tt * 32);
          xb1[jj] = *(const fx4*)(xr + tt * 32 + 4);
        }
      } else {
#pragma unroll
        for (int jj = 0; jj < 4; ++jj) {
          const short* up = &hb[wv - 1][(lt0 + jj) & 7][m15][8 * q];
          inA[jj] = *(const s16x8*)(up);
          inB[jj] = *(const s16x8*)(up + 32);
        }
      }
      // ---- 4 sequential steps (publish DEFERRED to interval end) ----
      s16x4 sv[4][4];                          // per-step tanh'd tiles (regs)
#pragma unroll
      for (int jj = 0; jj < 4; ++jj) {
        fx4 acc[4];
#pragma unroll
        for (int t4 = 0; t4 < 4; ++t4) acc[t4] = MFMA32(wiA[t4], inA[jj], z4);
        if (wv) {
#pragma unroll
          for (int t4 = 0; t4 < 4; ++t4) acc[t4] = MFMA32(wiB[t4], inB[jj], acc[t4]);
        }
#pragma unroll
        for (int t4 = 0; t4 < 4; ++t4) acc[t4] = MFMA32(wh32[t4][0], hA.v, acc[t4]);
#pragma unroll
        for (int t4 = 0; t4 < 4; ++t4) acc[t4] = MFMA32(wh32[t4][1], hB.v, acc[t4]);
        // tanh -> new own state; NO LDS traffic inside the serial section
        U8 nA, nB;
#pragma unroll
        for (int t4 = 0; t4 < 4; ++t4) {
          s16x4 hv = tanh_pack(acc[t4], bsc[t4]);
          sv[jj][t4] = hv;
          if (t4 < 2) nA.h[t4] = hv; else nB.h[t4 - 2] = hv;
        }
        hA = nA; hB = nB;
      }
      // ---- batched publish for downstream (layers 0,1 only): overlaps the
      // barrier drain; readers consume only after the next __syncthreads ----
      if (wv < 2) {
#pragma unroll
        for (int jj = 0; jj < 4; ++jj) {
          short* wb = &hb[wv][(lt0 + jj) & 7][m15][4 * q];
#pragma unroll
          for (int t4 = 0; t4 < 4; ++t4)
            *(s16x4*)(wb + 16 * t4) = sv[jj][t4];
        }
      }
    }
    __syncthreads();                          // ONE barrier per 4-step interval
  }

  // ---------- FC head: wave 2's state == h2(79), j = 16*kf + 4*q + i ----------
  if (wv == 2) {
    float sv2 = 0.f;
#pragma unroll
    for (int kf = 0; kf < 4; ++kf) {
      const s16x4 hh = (kf < 2) ? hA.h[kf] : hB.h[kf - 2];
#pragma unroll
      for (int i = 0; i < 4; ++i)
        sv2 += bf2f(hh[i]) * Wfc[16 * kf + 4 * q + i];
    }
    sv2 += __shfl_xor(sv2, 16, 64);
    sv2 += __shfl_xor(sv2, 32, 64);
    if (ln < 8) out[bbase + ln] = sv2 + bfc[0];   // 8 valid cols per block
  }
}

extern "C" void kernel_launch(void* const* d_in, const int* in_sizes, int n_in,
                              void* d_out, int out_size, void* d_ws, size_t ws_size,
                              hipStream_t stream) {
  const float* x    = (const float*)d_in[0];
  const float* Wih0 = (const float*)d_in[1];
  const float* Whh0 = (const float*)d_in[2];
  const float* bih0 = (const float*)d_in[3];
  const float* bhh0 = (const float*)d_in[4];
  const float* Wih1 = (const float*)d_in[5];
  const float* Whh1 = (const float*)d_in[6];
  const float* bih1 = (const float*)d_in[7];
  const float* bhh1 = (const float*)d_in[8];
  const float* Wih2 = (const float*)d_in[9];
  const float* Whh2 = (const float*)d_in[10];
  const float* bih2 = (const float*)d_in[11];
  const float* bhh2 = (const float*)d_in[12];
  const float* Wfc  = (const float*)d_in[13];
  const float* bfc  = (const float*)d_in[14];

  // 1024 blocks x 192 thr (3 waves = 3 pipelined layers), 8 valid rows/block:
  // 4 blocks/CU (LDS 147KB), 12 waves/CU = 3 waves/SIMD - stall-hiding via TLP.
  rnn3_half<<<dim3(1024), dim3(192), 0, stream>>>(
      x, Wih0, Whh0, bih0, bhh0, Wih1, Whh1, bih1, bhh1,
      Wih2, Whh2, bih2, bhh2, Wfc, bfc, (float*)d_out);
}

// Round 10
// 187.833 us; speedup vs baseline: 1.4872x; 1.4872x over previous
//
#include <hip/hip_runtime.h>
#include <hip/hip_bf16.h>
#include <cstddef>

// 3-layer tanh RNN (B=8192, T=80, D=32, H=64), fused, MFMA.
// SYSTOLIC LAYER PIPELINE, 4-STEP CHUNKS, register-carried recurrence (K=32).
// R21: SPLIT-ACCUMULATE - recurrence MFMA chain depth 4 -> 2 + VALU merge.
//
// R20 post-mortem: 2x streams -> 2x wall (issue-proportional), refuting
// latency-hiding-via-TLP; with R13 (fewer waves worse) the occupancy axis is
// closed both ways. Closed model: per 2-wave SIMD per step-slot (2060cyc),
// busy = 1200, BOTH waves idle ~860 simultaneously -> the serial item is the
// 4-deep chained-accumulate MFMA (wiA->wiB->wh0->wh1, D-as-C forwarding
// ~120cyc/link). This round: p = wiA.in(+wiB.in) [indep of recurrence,
// schedules into prev step's tanh shadow]; r = wh0.hA -> wh1.hB [depth 2];
// acc = p + r (16 v_add_f32). Same MFMA count; chain/step ~560 -> ~320 cyc.
// Numerics: one f32 reassociation (~1e-6), invisible at bf16 state precision.
//
// Structure (R18, best measured 73.5-75.2us):
//   - wave wv = layer wv; interval m (0..21): t = 4*(m-wv)..+3; ONE barrier
//     per interval; LDS ring hb[layer<2][t&7][16][72] (36864 B);
//     reader slots (lt0-4..-1)&7, writer (lt0..+3)&7, upstream (lt0+4..+7)&7
//     - pairwise disjoint mod 8;
//   - recurrence register-carried at K=32 via k-permuted Whh frags
//     (slot i = h[32h+16(i>>2)+4q+(i&3)], bijection folded into weight gather);
//   - wave-0 x double-buffered raw (fx4), packed at interval top, refill
//     issued after packing, consumed next interval;
//   - publishes deferred to interval end (R17);
//   - tanh: exp2 (bias pre-scaled by 2*log2e) + paired rcp (R18).
// MFMA maps (verified R2-R11):
//   K=32 A: A[m=lane&15][k=8q+i]; B: B[k=8q+i][n=lane&15]  (q=lane>>4)
//   16x16 D: D[row=4q+r][col=lane&15]

typedef __attribute__((ext_vector_type(8))) short s16x8;
typedef __attribute__((ext_vector_type(4))) short s16x4;
typedef __attribute__((ext_vector_type(4))) float fx4;

#define MFMA32(A, B, C) __builtin_amdgcn_mfma_f32_16x16x32_bf16((A), (B), (C), 0, 0, 0)

#if __has_builtin(__builtin_amdgcn_exp2f)
#define EXP2F(x) __builtin_amdgcn_exp2f(x)
#else
#define EXP2F(x) exp2f(x)
#endif
#if __has_builtin(__builtin_amdgcn_rcpf)
#define RCPF(x) __builtin_amdgcn_rcpf(x)
#else
#define RCPF(x) (1.0f / (x))
#endif

static constexpr float K2LOG2E = 2.8853900817779268f;  // 2*log2(e)

__device__ __forceinline__ short f2bf(float f) {  // RNE float->bf16 (weights, one-time)
  union { float f; unsigned u; } v; v.f = f;
  unsigned r = v.u + 0x7FFFu + ((v.u >> 16) & 1u);
  return (short)(r >> 16);
}
__device__ __forceinline__ float bf2f(short s) {
  union { unsigned u; float f; } v; v.u = ((unsigned)(unsigned short)s) << 16;
  return v.f;
}
__device__ __forceinline__ unsigned pk2bf(float a, float b) {  // v_cvt_pk_bf16_f32
  float2 t; t.x = a; t.y = b;
  union { __hip_bfloat162 h; unsigned u; } c;
  c.h = __float22bfloat162_rn(t);
  return c.u;
}

__device__ __forceinline__ s16x8 wfragA32(const float* W, int ncols, int row, int col0) {
  const float* p = W + row * ncols + col0;
  s16x8 r;
#pragma unroll
  for (int i = 0; i < 8; ++i) r[i] = f2bf(p[i]);
  return r;
}

// k-permuted Whh A-frag for the K=32 register-carried recurrence (half h=0,1):
// slot i  <-  Whh[row][ 32h + 16*(i>>2) + 4q + (i&3) ]
__device__ __forceinline__ s16x8 wfragWhh32(const float* W, int row, int q, int h) {
  const float* p = W + row * 64 + 32 * h + 4 * q;
  s16x8 r;
#pragma unroll
  for (int i = 0; i < 4; ++i) r[i] = f2bf(p[i]);
#pragma unroll
  for (int i = 0; i < 4; ++i) r[4 + i] = f2bf(p[16 + i]);
  return r;
}

// tanh(acc + bias) (bias pre-scaled by 2*log2e) -> packed bf16.
// PAIRED RCP: rp = rcp(a0*a1); 1/a0 = a1*rp; 1/a1 = a0*rp
__device__ __forceinline__ s16x4 tanh_pack(fx4 acc, const float* bs) {
  float a[4], h[4];
#pragma unroll
  for (int r = 0; r < 4; ++r)
    a[r] = EXP2F(__builtin_fmaf(acc[r], K2LOG2E, bs[r])) + 1.f;
#pragma unroll
  for (int pr = 0; pr < 2; ++pr) {
    float p  = a[2 * pr] * a[2 * pr + 1];
    float rp = RCPF(p);
    float m0 = a[2 * pr + 1] * rp;     // = 1/a0
    float m1 = a[2 * pr] * rp;         // = 1/a1
    h[2 * pr]     = __builtin_fmaf(-2.f, m0, 1.f);
    h[2 * pr + 1] = __builtin_fmaf(-2.f, m1, 1.f);
  }
  union { unsigned u[2]; s16x4 v; } pk;
  pk.u[0] = pk2bf(h[0], h[1]);
  pk.u[1] = pk2bf(h[2], h[3]);
  return pk.v;
}

union U8 { s16x8 v; s16x4 h[2]; };

__global__ __launch_bounds__(192, 2) void rnn3_split(
    const float* __restrict__ x,
    const float* __restrict__ Wih0, const float* __restrict__ Whh0,
    const float* __restrict__ bih0, const float* __restrict__ bhh0,
    const float* __restrict__ Wih1, const float* __restrict__ Whh1,
    const float* __restrict__ bih1, const float* __restrict__ bhh1,
    const float* __restrict__ Wih2, const float* __restrict__ Whh2,
    const float* __restrict__ bih2, const float* __restrict__ bhh2,
    const float* __restrict__ Wfc, const float* __restrict__ bfc,
    float* __restrict__ out)
{
  __shared__ __align__(16) short hb[2][8][16][72];  // [layer<2][t&7][batch][j], 36864 B

  const int tid = threadIdx.x;
  const int wv  = __builtin_amdgcn_readfirstlane(tid >> 6);  // 0..2 == layer
  const int ln  = tid & 63;
  const int q   = ln >> 4;        // K=32 k-quad / D row-quad
  const int m15 = ln & 15;
  const int bbase = (int)blockIdx.x * 16;

  // ---------- this wave's layer parameters ----------
  const float* Wih = (wv == 0) ? Wih0 : (wv == 1) ? Wih1 : Wih2;
  const float* Whh = (wv == 0) ? Whh0 : (wv == 1) ? Whh1 : Whh2;
  const float* bi  = (wv == 0) ? bih0 : (wv == 1) ? bih1 : bih2;
  const float* bh  = (wv == 0) ? bhh0 : (wv == 1) ? bhh1 : bhh2;
  const int kin = (wv == 0) ? 32 : 64;

  // ---------- weights (VGPR-resident) ----------
  s16x8 wiA[4], wiB[4];
  s16x8 wh32[4][2];
  const s16x8 z8 = {0, 0, 0, 0, 0, 0, 0, 0};
#pragma unroll
  for (int t4 = 0; t4 < 4; ++t4) {
    const int row = 16 * t4 + m15;
    wiA[t4] = wfragA32(Wih, kin, row, 8 * q);
    wiB[t4] = wv ? wfragA32(Wih, 64, row, 32 + 8 * q) : z8;   // layer 0: K=32 only
    wh32[t4][0] = wfragWhh32(Whh, row, q, 0);
    wh32[t4][1] = wfragWhh32(Whh, row, q, 1);
  }

  // ---------- biases pre-scaled; lane's j = 16*t4 + 4*q + r ----------
  float bsc[4][4];
#pragma unroll
  for (int t4 = 0; t4 < 4; ++t4)
#pragma unroll
    for (int r = 0; r < 4; ++r) {
      const int j = 16 * t4 + 4 * q + r;
      bsc[t4][r] = (bi[j] + bh[j]) * K2LOG2E;
    }

  const fx4 z4 = {0.f, 0.f, 0.f, 0.f};
  U8 hA, hB;                       // own state h_wv(t-1): hA=(j 0..31), hB=(j 32..63)
  hA.v = z8; hB.v = z8;

  // ---------- wave-0 x buffer: 4 t's of this interval (raw fx4) ----------
  const float* xr = x + (size_t)(bbase + m15) * (80 * 32) + 8 * q;
  fx4 xb0[4], xb1[4];
  if (wv == 0) {
#pragma unroll
    for (int jj = 0; jj < 4; ++jj) {          // preload t = 0..3
      xb0[jj] = *(const fx4*)(xr + jj * 32);
      xb1[jj] = *(const fx4*)(xr + jj * 32 + 4);
    }
  }

  for (int m = 0; m < 22; ++m) {
    const int lt0 = 4 * (m - wv);             // first t of this interval
    if (0 <= lt0 && lt0 <= 76) {              // wave-uniform
      // ---- interval top: gather all 4 inputs ----
      s16x8 inA[4], inB[4];
      if (wv == 0) {
#pragma unroll
        for (int jj = 0; jj < 4; ++jj) {
          union { unsigned u[4]; s16x8 v; } xp;
          xp.u[0] = pk2bf(xb0[jj][0], xb0[jj][1]);
          xp.u[1] = pk2bf(xb0[jj][2], xb0[jj][3]);
          xp.u[2] = pk2bf(xb1[jj][0], xb1[jj][1]);
          xp.u[3] = pk2bf(xb1[jj][2], xb1[jj][3]);
          inA[jj] = xp.v; inB[jj] = z8;
        }
        // refill for next interval (t = lt0+4 .. lt0+7, clamped); issued now,
        // consumed at NEXT interval top -> full interval to land
#pragma unroll
        for (int jj = 0; jj < 4; ++jj) {
          const int tt = (lt0 + 4 + jj <= 79) ? lt0 + 4 + jj : 79;
          xb0[jj] = *(const fx4*)(xr + tt * 32);
          xb1[jj] = *(const fx4*)(xr + tt * 32 + 4);
        }
      } else {
#pragma unroll
        for (int jj = 0; jj < 4; ++jj) {
          const short* up = &hb[wv - 1][(lt0 + jj) & 7][m15][8 * q];
          inA[jj] = *(const s16x8*)(up);
          inB[jj] = *(const s16x8*)(up + 32);
        }
      }
      // ---- 4 sequential steps: SPLIT-ACCUMULATE step body ----
      s16x4 sv[4][4];                          // per-step tanh'd tiles (regs)
#pragma unroll
      for (int jj = 0; jj < 4; ++jj) {
        // independent chain: input projection (no recurrence dependence;
        // schedules into the previous step's tanh shadow)
        fx4 p[4];
#pragma unroll
        for (int t4 = 0; t4 < 4; ++t4) p[t4] = MFMA32(wiA[t4], inA[jj], z4);
        if (wv) {
#pragma unroll
          for (int t4 = 0; t4 < 4; ++t4) p[t4] = MFMA32(wiB[t4], inB[jj], p[t4]);
        }
        // dependent chain, depth 2: recurrence
        fx4 r[4];
#pragma unroll
        for (int t4 = 0; t4 < 4; ++t4) r[t4] = MFMA32(wh32[t4][0], hA.v, z4);
#pragma unroll
        for (int t4 = 0; t4 < 4; ++t4) r[t4] = MFMA32(wh32[t4][1], hB.v, r[t4]);
        // merge + tanh -> new own state; NO LDS traffic in the serial section
        U8 nA, nB;
#pragma unroll
        for (int t4 = 0; t4 < 4; ++t4) {
          fx4 acc = p[t4] + r[t4];             // 4 v_add_f32 (pipelined)
          s16x4 hv = tanh_pack(acc, bsc[t4]);
          sv[jj][t4] = hv;
          if (t4 < 2) nA.h[t4] = hv; else nB.h[t4 - 2] = hv;
        }
        hA = nA; hB = nB;
      }
      // ---- batched publish for downstream (layers 0,1 only): overlaps the
      // barrier drain; readers consume only after the next __syncthreads ----
      if (wv < 2) {
#pragma unroll
        for (int jj = 0; jj < 4; ++jj) {
          short* wb = &hb[wv][(lt0 + jj) & 7][m15][4 * q];
#pragma unroll
          for (int t4 = 0; t4 < 4; ++t4)
            *(s16x4*)(wb + 16 * t4) = sv[jj][t4];
        }
      }
    }
    __syncthreads();                          // ONE barrier per 4-step interval
  }

  // ---------- FC head: wave 2's state == h2(79), j = 16*kf + 4*q + i ----------
  if (wv == 2) {
    float sv2 = 0.f;
#pragma unroll
    for (int kf = 0; kf < 4; ++kf) {
      const s16x4 hh = (kf < 2) ? hA.h[kf] : hB.h[kf - 2];
#pragma unroll
      for (int i = 0; i < 4; ++i)
        sv2 += bf2f(hh[i]) * Wfc[16 * kf + 4 * q + i];
    }
    sv2 += __shfl_xor(sv2, 16, 64);
    sv2 += __shfl_xor(sv2, 32, 64);
    if (ln < 16) out[bbase + ln] = sv2 + bfc[0];
  }
}

extern "C" void kernel_launch(void* const* d_in, const int* in_sizes, int n_in,
                              void* d_out, int out_size, void* d_ws, size_t ws_size,
                              hipStream_t stream) {
  const float* x    = (const float*)d_in[0];
  const float* Wih0 = (const float*)d_in[1];
  const float* Whh0 = (const float*)d_in[2];
  const float* bih0 = (const float*)d_in[3];
  const float* bhh0 = (const float*)d_in[4];
  const float* Wih1 = (const float*)d_in[5];
  const float* Whh1 = (const float*)d_in[6];
  const float* bih1 = (const float*)d_in[7];
  const float* bhh1 = (const float*)d_in[8];
  const float* Wih2 = (const float*)d_in[9];
  const float* Whh2 = (const float*)d_in[10];
  const float* bih2 = (const float*)d_in[11];
  const float* bhh2 = (const float*)d_in[12];
  const float* Wfc  = (const float*)d_in[13];
  const float* bfc  = (const float*)d_in[14];

  // 512 blocks x 192 thr (3 waves = 3 pipelined layers), 16 batch rows/block:
  // 2 blocks/CU, 1.5 waves/SIMD (R12 config - best measured).
  rnn3_split<<<dim3(512), dim3(192), 0, stream>>>(
      x, Wih0, Whh0, bih0, bhh0, Wih1, Whh1, bih1, bhh1,
      Wih2, Whh2, bih2, bhh2, Wfc, bfc, (float*)d_out);
}

// Round 11
// 185.598 us; speedup vs baseline: 1.5051x; 1.0120x over previous
//
#include <hip/hip_runtime.h>
#include <hip/hip_bf16.h>
#include <cstddef>

// 3-layer tanh RNN (B=8192, T=80, D=32, H=64), fused, MFMA.
// SYSTOLIC LAYER PIPELINE, 4-STEP CHUNKS, register-carried recurrence (K=32).
// R22: RESTORE R18 (best measured: 73.5-75.2us dispatch) after R19-R21 probes
// all regressed. This kernel is the measured local optimum of the structure.
//
// Closure log (what was probed and why it lost):
//   R13 fewer waves (0.75/SIMD): -40% (idle SIMD + exposed latency)
//   R14 LUT tanh: -29% (equal VALU + 10M bank conflicts; trans was not wall)
//   R15 hoisted input-proj MFMAs: -16% (killed compiler's cross-step overlap)
//   R16 CH=8: -8% (fill/drain 2CH slots > barrier F saved; F~0.38k, s~1.96k)
//   R19 late-pack x: -3% (wave-0 tail ran past other waves' publish)
//   R20 3 waves/SIMD: confounded (spills + 2x fetch), but closed on
//       arithmetic: duplicated tiles 2x work vs packing gain bound <1.3x
//   R21 split-accumulate (chain 4->2): -5% (chain latency not the wall)
// Counter-closed model: pace = 2-wave SIMDs at ~2000 cyc/step-slot vs
// 2x780 issue work (VALU 560 + MFMA 220 per wave-step); ~78% dual-issue
// packing; residual = dependency bubbles + F~380/interval convergence.
// tanh at minimal op count (exp2+paired-rcp; poly needs deg~19 on [-4,4]).
// Streams fixed at 1536 by MFMA N=16 and 3 layers; 6 waves/CU => 2,2,1,1.
//
// Structure:
//   - wave wv = layer wv; interval m (0..21): t = 4*(m-wv)..+3; ONE barrier
//     per interval; LDS ring hb[layer<2][t&7][16][72] (36864 B);
//     reader slots (lt0-4..-1)&7, writer (lt0..+3)&7, upstream (lt0+4..+7)&7
//     - pairwise disjoint mod 8;
//   - recurrence register-carried at K=32 via k-permuted Whh frags
//     (slot i = h[32h+16(i>>2)+4q+(i&3)], bijection folded into weight gather);
//   - wave-0 x double-buffered raw (fx4), packed at interval top, refill
//     issued after packing, consumed next interval;
//   - publishes deferred to interval end (R17, overlaps barrier drain);
//   - tanh: exp2 (bias pre-scaled by 2*log2e) + paired rcp (R18).
// MFMA maps (verified R2-R11):
//   K=32 A: A[m=lane&15][k=8q+i]; B: B[k=8q+i][n=lane&15]  (q=lane>>4)
//   16x16 D: D[row=4q+r][col=lane&15]

typedef __attribute__((ext_vector_type(8))) short s16x8;
typedef __attribute__((ext_vector_type(4))) short s16x4;
typedef __attribute__((ext_vector_type(4))) float fx4;

#define MFMA32(A, B, C) __builtin_amdgcn_mfma_f32_16x16x32_bf16((A), (B), (C), 0, 0, 0)

#if __has_builtin(__builtin_amdgcn_exp2f)
#define EXP2F(x) __builtin_amdgcn_exp2f(x)
#else
#define EXP2F(x) exp2f(x)
#endif
#if __has_builtin(__builtin_amdgcn_rcpf)
#define RCPF(x) __builtin_amdgcn_rcpf(x)
#else
#define RCPF(x) (1.0f / (x))
#endif

static constexpr float K2LOG2E = 2.8853900817779268f;  // 2*log2(e)

__device__ __forceinline__ short f2bf(float f) {  // RNE float->bf16 (weights, one-time)
  union { float f; unsigned u; } v; v.f = f;
  unsigned r = v.u + 0x7FFFu + ((v.u >> 16) & 1u);
  return (short)(r >> 16);
}
__device__ __forceinline__ float bf2f(short s) {
  union { unsigned u; float f; } v; v.u = ((unsigned)(unsigned short)s) << 16;
  return v.f;
}
__device__ __forceinline__ unsigned pk2bf(float a, float b) {  // v_cvt_pk_bf16_f32
  float2 t; t.x = a; t.y = b;
  union { __hip_bfloat162 h; unsigned u; } c;
  c.h = __float22bfloat162_rn(t);
  return c.u;
}

__device__ __forceinline__ s16x8 wfragA32(const float* W, int ncols, int row, int col0) {
  const float* p = W + row * ncols + col0;
  s16x8 r;
#pragma unroll
  for (int i = 0; i < 8; ++i) r[i] = f2bf(p[i]);
  return r;
}

// k-permuted Whh A-frag for the K=32 register-carried recurrence (half h=0,1):
// slot i  <-  Whh[row][ 32h + 16*(i>>2) + 4q + (i&3) ]
__device__ __forceinline__ s16x8 wfragWhh32(const float* W, int row, int q, int h) {
  const float* p = W + row * 64 + 32 * h + 4 * q;
  s16x8 r;
#pragma unroll
  for (int i = 0; i < 4; ++i) r[i] = f2bf(p[i]);
#pragma unroll
  for (int i = 0; i < 4; ++i) r[4 + i] = f2bf(p[16 + i]);
  return r;
}

// tanh(acc + bias) (bias pre-scaled by 2*log2e) -> packed bf16.
// PAIRED RCP: rp = rcp(a0*a1); 1/a0 = a1*rp; 1/a1 = a0*rp
__device__ __forceinline__ s16x4 tanh_pack(fx4 acc, const float* bs) {
  float a[4], h[4];
#pragma unroll
  for (int r = 0; r < 4; ++r)
    a[r] = EXP2F(__builtin_fmaf(acc[r], K2LOG2E, bs[r])) + 1.f;
#pragma unroll
  for (int pr = 0; pr < 2; ++pr) {
    float p  = a[2 * pr] * a[2 * pr + 1];
    float rp = RCPF(p);
    float m0 = a[2 * pr + 1] * rp;     // = 1/a0
    float m1 = a[2 * pr] * rp;         // = 1/a1
    h[2 * pr]     = __builtin_fmaf(-2.f, m0, 1.f);
    h[2 * pr + 1] = __builtin_fmaf(-2.f, m1, 1.f);
  }
  union { unsigned u[2]; s16x4 v; } pk;
  pk.u[0] = pk2bf(h[0], h[1]);
  pk.u[1] = pk2bf(h[2], h[3]);
  return pk.v;
}

union U8 { s16x8 v; s16x4 h[2]; };

__global__ __launch_bounds__(192, 2) void rnn3_final(
    const float* __restrict__ x,
    const float* __restrict__ Wih0, const float* __restrict__ Whh0,
    const float* __restrict__ bih0, const float* __restrict__ bhh0,
    const float* __restrict__ Wih1, const float* __restrict__ Whh1,
    const float* __restrict__ bih1, const float* __restrict__ bhh1,
    const float* __restrict__ Wih2, const float* __restrict__ Whh2,
    const float* __restrict__ bih2, const float* __restrict__ bhh2,
    const float* __restrict__ Wfc, const float* __restrict__ bfc,
    float* __restrict__ out)
{
  __shared__ __align__(16) short hb[2][8][16][72];  // [layer<2][t&7][batch][j], 36864 B

  const int tid = threadIdx.x;
  const int wv  = __builtin_amdgcn_readfirstlane(tid >> 6);  // 0..2 == layer
  const int ln  = tid & 63;
  const int q   = ln >> 4;        // K=32 k-quad / D row-quad
  const int m15 = ln & 15;
  const int bbase = (int)blockIdx.x * 16;

  // ---------- this wave's layer parameters ----------
  const float* Wih = (wv == 0) ? Wih0 : (wv == 1) ? Wih1 : Wih2;
  const float* Whh = (wv == 0) ? Whh0 : (wv == 1) ? Whh1 : Whh2;
  const float* bi  = (wv == 0) ? bih0 : (wv == 1) ? bih1 : bih2;
  const float* bh  = (wv == 0) ? bhh0 : (wv == 1) ? bhh1 : bhh2;
  const int kin = (wv == 0) ? 32 : 64;

  // ---------- weights (VGPR-resident) ----------
  s16x8 wiA[4], wiB[4];
  s16x8 wh32[4][2];
  const s16x8 z8 = {0, 0, 0, 0, 0, 0, 0, 0};
#pragma unroll
  for (int t4 = 0; t4 < 4; ++t4) {
    const int row = 16 * t4 + m15;
    wiA[t4] = wfragA32(Wih, kin, row, 8 * q);
    wiB[t4] = wv ? wfragA32(Wih, 64, row, 32 + 8 * q) : z8;   // layer 0: K=32 only
    wh32[t4][0] = wfragWhh32(Whh, row, q, 0);
    wh32[t4][1] = wfragWhh32(Whh, row, q, 1);
  }

  // ---------- biases pre-scaled; lane's j = 16*t4 + 4*q + r ----------
  float bsc[4][4];
#pragma unroll
  for (int t4 = 0; t4 < 4; ++t4)
#pragma unroll
    for (int r = 0; r < 4; ++r) {
      const int j = 16 * t4 + 4 * q + r;
      bsc[t4][r] = (bi[j] + bh[j]) * K2LOG2E;
    }

  const fx4 z4 = {0.f, 0.f, 0.f, 0.f};
  U8 hA, hB;                       // own state h_wv(t-1): hA=(j 0..31), hB=(j 32..63)
  hA.v = z8; hB.v = z8;

  // ---------- wave-0 x buffer: 4 t's of this interval (raw fx4) ----------
  const float* xr = x + (size_t)(bbase + m15) * (80 * 32) + 8 * q;
  fx4 xb0[4], xb1[4];
  if (wv == 0) {
#pragma unroll
    for (int jj = 0; jj < 4; ++jj) {          // preload t = 0..3
      xb0[jj] = *(const fx4*)(xr + jj * 32);
      xb1[jj] = *(const fx4*)(xr + jj * 32 + 4);
    }
  }

  for (int m = 0; m < 22; ++m) {
    const int lt0 = 4 * (m - wv);             // first t of this interval
    if (0 <= lt0 && lt0 <= 76) {              // wave-uniform
      // ---- interval top: gather all 4 inputs ----
      s16x8 inA[4], inB[4];
      if (wv == 0) {
#pragma unroll
        for (int jj = 0; jj < 4; ++jj) {
          union { unsigned u[4]; s16x8 v; } xp;
          xp.u[0] = pk2bf(xb0[jj][0], xb0[jj][1]);
          xp.u[1] = pk2bf(xb0[jj][2], xb0[jj][3]);
          xp.u[2] = pk2bf(xb1[jj][0], xb1[jj][1]);
          xp.u[3] = pk2bf(xb1[jj][2], xb1[jj][3]);
          inA[jj] = xp.v; inB[jj] = z8;
        }
        // refill for next interval (t = lt0+4 .. lt0+7, clamped); issued now,
        // consumed at NEXT interval top -> full interval to land
#pragma unroll
        for (int jj = 0; jj < 4; ++jj) {
          const int tt = (lt0 + 4 + jj <= 79) ? lt0 + 4 + jj : 79;
          xb0[jj] = *(const fx4*)(xr + tt * 32);
          xb1[jj] = *(const fx4*)(xr + tt * 32 + 4);
        }
      } else {
#pragma unroll
        for (int jj = 0; jj < 4; ++jj) {
          const short* up = &hb[wv - 1][(lt0 + jj) & 7][m15][8 * q];
          inA[jj] = *(const s16x8*)(up);
          inB[jj] = *(const s16x8*)(up + 32);
        }
      }
      // ---- 4 sequential steps (publish DEFERRED to interval end) ----
      s16x4 sv[4][4];                          // per-step tanh'd tiles (regs)
#pragma unroll
      for (int jj = 0; jj < 4; ++jj) {
        fx4 acc[4];
#pragma unroll
        for (int t4 = 0; t4 < 4; ++t4) acc[t4] = MFMA32(wiA[t4], inA[jj], z4);
        if (wv) {
#pragma unroll
          for (int t4 = 0; t4 < 4; ++t4) acc[t4] = MFMA32(wiB[t4], inB[jj], acc[t4]);
        }
#pragma unroll
        for (int t4 = 0; t4 < 4; ++t4) acc[t4] = MFMA32(wh32[t4][0], hA.v, acc[t4]);
#pragma unroll
        for (int t4 = 0; t4 < 4; ++t4) acc[t4] = MFMA32(wh32[t4][1], hB.v, acc[t4]);
        // tanh -> new own state; NO LDS traffic inside the serial section
        U8 nA, nB;
#pragma unroll
        for (int t4 = 0; t4 < 4; ++t4) {
          s16x4 hv = tanh_pack(acc[t4], bsc[t4]);
          sv[jj][t4] = hv;
          if (t4 < 2) nA.h[t4] = hv; else nB.h[t4 - 2] = hv;
        }
        hA = nA; hB = nB;
      }
      // ---- batched publish for downstream (layers 0,1 only): overlaps the
      // barrier drain; readers consume only after the next __syncthreads ----
      if (wv < 2) {
#pragma unroll
        for (int jj = 0; jj < 4; ++jj) {
          short* wb = &hb[wv][(lt0 + jj) & 7][m15][4 * q];
#pragma unroll
          for (int t4 = 0; t4 < 4; ++t4)
            *(s16x4*)(wb + 16 * t4) = sv[jj][t4];
        }
      }
    }
    __syncthreads();                          // ONE barrier per 4-step interval
  }

  // ---------- FC head: wave 2's state == h2(79), j = 16*kf + 4*q + i ----------
  if (wv == 2) {
    float sv2 = 0.f;
#pragma unroll
    for (int kf = 0; kf < 4; ++kf) {
      const s16x4 hh = (kf < 2) ? hA.h[kf] : hB.h[kf - 2];
#pragma unroll
      for (int i = 0; i < 4; ++i)
        sv2 += bf2f(hh[i]) * Wfc[16 * kf + 4 * q + i];
    }
    sv2 += __shfl_xor(sv2, 16, 64);
    sv2 += __shfl_xor(sv2, 32, 64);
    if (ln < 16) out[bbase + ln] = sv2 + bfc[0];
  }
}

extern "C" void kernel_launch(void* const* d_in, const int* in_sizes, int n_in,
                              void* d_out, int out_size, void* d_ws, size_t ws_size,
                              hipStream_t stream) {
  const float* x    = (const float*)d_in[0];
  const float* Wih0 = (const float*)d_in[1];
  const float* Whh0 = (const float*)d_in[2];
  const float* bih0 = (const float*)d_in[3];
  const float* bhh0 = (const float*)d_in[4];
  const float* Wih1 = (const float*)d_in[5];
  const float* Whh1 = (const float*)d_in[6];
  const float* bih1 = (const float*)d_in[7];
  const float* bhh1 = (const float*)d_in[8];
  const float* Wih2 = (const float*)d_in[9];
  const float* Whh2 = (const float*)d_in[10];
  const float* bih2 = (const float*)d_in[11];
  const float* bhh2 = (const float*)d_in[12];
  const float* Wfc  = (const float*)d_in[13];
  const float* bfc  = (const float*)d_in[14];

  // 512 blocks x 192 thr (3 waves = 3 pipelined layers), 16 batch rows/block:
  // 2 blocks/CU, 1.5 waves/SIMD (best measured config, R12-R21 closure).
  rnn3_final<<<dim3(512), dim3(192), 0, stream>>>(
      x, Wih0, Whh0, bih0, bhh0, Wih1, Whh1, bih1, bhh1,
      Wih2, Whh2, bih2, bhh2, Wfc, bfc, (float*)d_out);
}